// Round 1
// baseline (711.879 us; speedup 1.0000x reference)
//
#include <hip/hip_runtime.h>
#include <stdint.h>

// ---------------- problem constants ----------------
#define B_   4
#define A_   25200
#define NC_  80
#define ROW_ 85          // 5 + NC
#define ATT_ 980         // 5 * 14 * 14
#define MAXDET_ 100
#define TOPK_ 1024
#define CAP_  4096       // candidate buffer per batch (expected ~1.6K)
#define OUTSTRIDE_ 25606 // 4 + 1 + 1 + 160*160
#define HW_ 160
#define HWHW_ 25600
#define CONF_ 0.25f
#define IOUT_ 0.45f

// ---------------- workspace layout (bytes) ----------------
#define WS_HIST 0         // 4 * 256 u32
#define WS_CNT  4096      // 4 u32
#define WS_TB   4160      // 4 i32
#define WS_NTOP 4224      // 4 i32
#define WS_CAND 8192      // 4 * 4096 u64
#define WS_TOPV 139264    // 4 * 1024 f32
#define WS_TOPA 155648    // 4 * 1024 i32 (anchor)
#define WS_TOPC 172032    // 4 * 1024 i32 (class)
#define WS_CB   188416    // 4 * 1024 float4 (boxes)
#define WS_SUP  253952    // 4 * 1024 * 16 u64
#define WS_DETA 778240    // 400 i32 (selected anchor per det slot)
// total ~780 KB

typedef unsigned long long u64;
typedef unsigned u32;

// ---------------- K0: clear hist + counters ----------------
__global__ void k_clear(char* w) {
    int i = blockIdx.x * 256 + threadIdx.x;
    if (i < 1028) ((u32*)w)[i] = 0u;   // hist (1024 words) + cnt (4 words)
}

// ---------------- K1: score histogram (float-bit buckets) ----------------
__global__ void k_hist(const float* __restrict__ test, char* __restrict__ w) {
    int b = blockIdx.y;
    __shared__ u32 h[256];
    if (threadIdx.x < 256) h[threadIdx.x] = 0u;
    __syncthreads();
    const int total = A_ * NC_;
    for (int e = blockIdx.x * 256 + threadIdx.x; e < total; e += 128 * 256) {
        u32 a = (u32)e / 80u;
        u32 c = (u32)e - a * 80u;
        const float* row = test + ((size_t)b * A_ + a) * ROW_;
        float s = row[5 + c] * row[4];
        if (s > CONF_) {
            u32 key = __float_as_uint(s);
            int wb = (int)(key >> 17) - 7936;
            wb = wb < 0 ? 0 : (wb > 255 ? 255 : wb);
            atomicAdd(&h[wb], 1u);
        }
    }
    __syncthreads();
    u32* hist = (u32*)(w + WS_HIST);
    if (threadIdx.x < 256 && h[threadIdx.x]) atomicAdd(&hist[b * 256 + threadIdx.x], h[threadIdx.x]);
}

// ---------------- K2: find threshold bucket for rank TOPK ----------------
__global__ void k_thresh(char* w) {
    if (threadIdx.x < B_) {
        int b = threadIdx.x;
        const u32* h = (const u32*)(w + WS_HIST) + b * 256;
        u32 cum = 0; int wtb = 0;
        for (int i = 255; i >= 0; --i) {
            cum += h[i];
            if (cum >= TOPK_) { wtb = i; break; }
        }
        ((int*)(w + WS_TB))[b] = wtb;
    }
}

// ---------------- K3: collect candidates >= threshold bucket ----------------
__global__ void k_collect(const float* __restrict__ test, char* __restrict__ w) {
    int b = blockIdx.y;
    int wtb = ((const int*)(w + WS_TB))[b];
    u32* cnt = (u32*)(w + WS_CNT);
    u64* cand = (u64*)(w + WS_CAND);
    const int total = A_ * NC_;
    for (int e = blockIdx.x * 256 + threadIdx.x; e < total; e += 128 * 256) {
        u32 a = (u32)e / 80u;
        u32 c = (u32)e - a * 80u;
        const float* row = test + ((size_t)b * A_ + a) * ROW_;
        float s = row[5 + c] * row[4];
        if (s > CONF_) {
            u32 key = __float_as_uint(s);
            int wb = (int)(key >> 17) - 7936;
            wb = wb < 0 ? 0 : (wb > 255 ? 255 : wb);
            if (wb >= wtb) {
                u32 pos = atomicAdd(&cnt[b], 1u);
                if (pos < CAP_)
                    cand[(size_t)b * CAP_ + pos] = ((u64)key << 32) | (u64)(0xFFFFFFFFu - (u32)e);
            }
        }
    }
}

// ---------------- K4: per-batch bitonic sort -> exact top-1024 ----------------
__global__ __launch_bounds__(1024) void k_sort(const float* __restrict__ test, char* __restrict__ w) {
    int b = blockIdx.x;
    __shared__ u64 sm[CAP_];
    u32 cnt = ((const u32*)(w + WS_CNT))[b];
    int n = cnt < CAP_ ? (int)cnt : CAP_;
    const u64* cand = (const u64*)(w + WS_CAND) + (size_t)b * CAP_;
    for (int i = threadIdx.x; i < CAP_; i += 1024) sm[i] = (i < n) ? cand[i] : 0ull;
    __syncthreads();
    // bitonic sort, descending (key desc, then smaller idx first via ~idx in low bits)
    for (int k = 2; k <= CAP_; k <<= 1) {
        for (int j = k >> 1; j > 0; j >>= 1) {
            for (int t = threadIdx.x; t < CAP_; t += 1024) {
                int ixj = t ^ j;
                if (ixj > t) {
                    u64 a = sm[t], c = sm[ixj];
                    bool desc = ((t & k) == 0);
                    if (desc ? (a < c) : (a > c)) { sm[t] = c; sm[ixj] = a; }
                }
            }
            __syncthreads();
        }
    }
    int ntop = n < TOPK_ ? n : TOPK_;
    if (threadIdx.x == 0) ((int*)(w + WS_NTOP))[b] = ntop;
    if (threadIdx.x < TOPK_) {
        int i = threadIdx.x;
        float* topv = (float*)(w + WS_TOPV);
        int* topa = (int*)(w + WS_TOPA);
        int* topc = (int*)(w + WS_TOPC);
        float4* cb = (float4*)(w + WS_CB);
        if (i < ntop) {
            u64 v = sm[i];
            u32 key = (u32)(v >> 32);
            u32 idx = 0xFFFFFFFFu - (u32)(v & 0xFFFFFFFFull);
            u32 anchor = idx / 80u;
            u32 cls = idx - anchor * 80u;
            const float* tr = test + ((size_t)b * A_ + anchor) * ROW_;
            float cx = tr[0], cy = tr[1], ww = tr[2], hh = tr[3];
            float4 box;
            box.x = cx - 0.5f * ww; box.y = cy - 0.5f * hh;
            box.z = cx + 0.5f * ww; box.w = cy + 0.5f * hh;
            topv[b * TOPK_ + i] = __uint_as_float(key);
            topa[b * TOPK_ + i] = (int)anchor;
            topc[b * TOPK_ + i] = (int)cls;
            cb[b * TOPK_ + i] = box;
        } else {
            topv[b * TOPK_ + i] = 0.f;
            topa[b * TOPK_ + i] = 0;
            topc[b * TOPK_ + i] = 0;
            cb[b * TOPK_ + i] = make_float4(0.f, 0.f, 0.f, 0.f);
        }
    }
}

// exact-numpy IoU suppression test (no FMA contraction -> matches np bitwise)
__device__ __forceinline__ bool sup_pair(float4 a, float4 b, int ca, int cbb) {
#pragma clang fp contract(off)
    if (ca != cbb) return false;
    float areaA = fmaxf(a.z - a.x, 0.f) * fmaxf(a.w - a.y, 0.f);
    float areaB = fmaxf(b.z - b.x, 0.f) * fmaxf(b.w - b.y, 0.f);
    float ltx = fmaxf(a.x, b.x), lty = fmaxf(a.y, b.y);
    float rbx = fminf(a.z, b.z), rby = fminf(a.w, b.w);
    float iw = fmaxf(rbx - ltx, 0.f), ih = fmaxf(rby - lty, 0.f);
    float inter = iw * ih;
    float iou = inter / (((areaA + areaB) - inter) + 1e-9f);
    return iou > IOUT_;
}

// ---------------- K5: suppression bit-matrix ----------------
__global__ void k_sup(char* __restrict__ w) {
    int b = blockIdx.y;
    int t = blockIdx.x * 256 + threadIdx.x;   // 0..16383
    int row = t >> 4, chunk = t & 15;
    const float4* cb = (const float4*)(w + WS_CB) + (size_t)b * TOPK_;
    const int* topc = (const int*)(w + WS_TOPC) + (size_t)b * TOPK_;
    float4 rb = cb[row];
    int rc = topc[row];
    u64 bits = 0ull;
    int base = chunk * 64;
    for (int cc = 0; cc < 64; ++cc) {
        if (sup_pair(rb, cb[base + cc], rc, topc[base + cc])) bits |= (1ull << cc);
    }
    ((u64*)(w + WS_SUP))[((size_t)b * TOPK_ + row) * 16 + chunk] = bits;
}

// ---------------- K6: greedy NMS (one wave per batch) + header writes ----------------
__global__ void k_nms(char* __restrict__ w, float* __restrict__ out) {
    int b = blockIdx.x;
    int lane = threadIdx.x;   // 64 lanes
    int ntop = ((const int*)(w + WS_NTOP))[b];
    const u64* sup = (const u64*)(w + WS_SUP);
    __shared__ int selA[MAXDET_];
    __shared__ int okA[MAXDET_];
    u32 valid = 0u;
    for (int t = 0; t < 16; ++t)
        if (lane * 16 + t < ntop) valid |= (1u << t);
    for (int k = 0; k < MAXDET_; ++k) {
        u64 bal = __ballot(valid != 0u);
        if (bal == 0ull) {
            if (lane == 0) { selA[k] = 0; okA[k] = 0; }
            continue;
        }
        int L = __ffsll(bal) - 1;
        u32 vL = (u32)__shfl((int)valid, L);
        int j = L * 16 + (__ffs(vL & 0xFFFFu) - 1);
        u64 chunk = sup[((size_t)b * TOPK_ + j) * 16 + (lane >> 2)];
        u32 s16 = (u32)(chunk >> ((lane & 3) * 16)) & 0xFFFFu;
        valid &= ~s16;
        if (lane == L) valid &= ~(1u << (j & 15));
        if (lane == 0) { selA[k] = j; okA[k] = 1; }
    }
    __syncthreads();
    const float* topv = (const float*)(w + WS_TOPV) + (size_t)b * TOPK_;
    const int* topa = (const int*)(w + WS_TOPA) + (size_t)b * TOPK_;
    const int* topc = (const int*)(w + WS_TOPC) + (size_t)b * TOPK_;
    const float4* cb = (const float4*)(w + WS_CB) + (size_t)b * TOPK_;
    int* deta = (int*)(w + WS_DETA);
    for (int k = lane; k < MAXDET_; k += 64) {
        int ok = okA[k], s = selA[k];
        float b0 = 0, b1 = 0, b2 = 0, b3 = 0, sc = 0; int cls_ = 0, anc = 0;
        if (ok) {
            float4 bb = cb[s];
            b0 = bb.x; b1 = bb.y; b2 = bb.z; b3 = bb.w;
            sc = topv[s]; cls_ = topc[s]; anc = topa[s];
        }
        size_t o = ((size_t)(b * MAXDET_ + k)) * OUTSTRIDE_;
        out[o + 0] = b0; out[o + 1] = b1; out[o + 2] = b2; out[o + 3] = b3;
        out[o + 4] = sc; out[o + 5] = (float)cls_;
        deta[b * MAXDET_ + k] = anc;
    }
}

// ---------------- K7: ROI-align + coeff-resize + softmax + sigmoid masks ----------------
__global__ void k_mask(const float* __restrict__ test, const float* __restrict__ attn,
                       const float* __restrict__ bases, const float* __restrict__ sem,
                       const char* __restrict__ w, float* __restrict__ out) {
    int roi = blockIdx.x;          // 0..399
    int b = roi / MAXDET_;
    int anchor = ((const int*)(w + WS_DETA))[roi];
    const float* t = test + ((size_t)b * A_ + anchor) * ROW_;
    float cx = t[0], cy = t[1], ww = t[2], hh = t[3];
    float bx1 = cx - 0.5f * ww, by1 = cy - 0.5f * hh;
    float bx2 = cx + 0.5f * ww, by2 = cy + 0.5f * hh;
    float rx1 = bx1 * 0.25f - 0.5f, ry1 = by1 * 0.25f - 0.5f;
    float rx2 = bx2 * 0.25f - 0.5f, ry2 = by2 * 0.25f - 0.5f;
    float xstep = (rx2 - rx1) / 160.f, ystep = (ry2 - ry1) / 160.f;

    __shared__ float att[5 * 196];
    __shared__ float sxw[HW_], syw[HW_], rzw[HW_];
    __shared__ int sxlo[HW_], sxhi[HW_], sylo[HW_], syhi[HW_];
    __shared__ int sxv[HW_], syv[HW_], rzlo[HW_];

    const float* arow = attn + ((size_t)b * A_ + anchor) * ATT_;
    for (int i = threadIdx.x; i < ATT_; i += 256) att[i] = arow[i];
    if (threadIdx.x < HW_) {
        int i = threadIdx.x;
        float coord = rx1 + (i + 0.5f) * xstep;
        sxv[i] = (coord > -1.0f) && (coord < 160.0f);
        float c = fminf(fmaxf(coord, 0.f), 159.f);
        float lo = floorf(c);
        sxlo[i] = (int)lo; sxhi[i] = min((int)lo + 1, 159); sxw[i] = c - lo;
        coord = ry1 + (i + 0.5f) * ystep;
        syv[i] = (coord > -1.0f) && (coord < 160.0f);
        c = fminf(fmaxf(coord, 0.f), 159.f);
        lo = floorf(c);
        sylo[i] = (int)lo; syhi[i] = min((int)lo + 1, 159); syw[i] = c - lo;
        // 14 -> 160 half-pixel linear resize (clamped == jax normalized triangle)
        float f = (i + 0.5f) * (14.f / 160.f) - 0.5f;
        float rc = fminf(fmaxf(f, 0.f), 13.f);
        float rlo = floorf(rc);
        rzlo[i] = (int)rlo; rzw[i] = rc - rlo;
    }
    __syncthreads();

    const float* bp[5];
    bp[0] = bases + ((size_t)b * 4 + 0) * HWHW_;
    bp[1] = bases + ((size_t)b * 4 + 1) * HWHW_;
    bp[2] = bases + ((size_t)b * 4 + 2) * HWHW_;
    bp[3] = bases + ((size_t)b * 4 + 3) * HWHW_;
    bp[4] = sem + (size_t)b * HWHW_;

    size_t obase = (size_t)roi * OUTSTRIDE_ + 6;
    int pstart = blockIdx.y * (HWHW_ / 8);
    int pend = pstart + (HWHW_ / 8);
    for (int p = pstart + (int)threadIdx.x; p < pend; p += 256) {
        int y = p / HW_, x = p - y * HW_;
        int ylo = sylo[y], yhi = syhi[y]; float wy = syw[y];
        int xlo = sxlo[x], xhi = sxhi[x]; float wx = sxw[x];
        bool v = sxv[x] && syv[y];
        float w00 = (1.f - wy) * (1.f - wx), w01 = (1.f - wy) * wx;
        float w10 = wy * (1.f - wx), w11 = wy * wx;
        int i00 = ylo * HW_ + xlo, i01 = ylo * HW_ + xhi;
        int i10 = yhi * HW_ + xlo, i11 = yhi * HW_ + xhi;
        float pooled[5];
#pragma unroll
        for (int c5 = 0; c5 < 5; ++c5) {
            float g = bp[c5][i00] * w00 + bp[c5][i01] * w01 + bp[c5][i10] * w10 + bp[c5][i11] * w11;
            pooled[c5] = v ? g : 0.f;
        }
        int cylo = rzlo[y]; float cwy = rzw[y]; int cyhi = min(cylo + 1, 13);
        int cxlo = rzlo[x]; float cwx = rzw[x]; int cxhi = min(cxlo + 1, 13);
        float c00 = (1.f - cwy) * (1.f - cwx), c01 = (1.f - cwy) * cwx;
        float c10 = cwy * (1.f - cwx), c11 = cwy * cwx;
        int j00 = cylo * 14 + cxlo, j01 = cylo * 14 + cxhi;
        int j10 = cyhi * 14 + cxlo, j11 = cyhi * 14 + cxhi;
        float cf[5]; float m = -1e30f;
#pragma unroll
        for (int c5 = 0; c5 < 5; ++c5) {
            const float* ap = att + c5 * 196;
            float g = ap[j00] * c00 + ap[j01] * c01 + ap[j10] * c10 + ap[j11] * c11;
            cf[c5] = g; m = fmaxf(m, g);
        }
        float se = 0.f, dot = 0.f;
#pragma unroll
        for (int c5 = 0; c5 < 5; ++c5) {
            float e = __expf(cf[c5] - m);
            se += e; dot += pooled[c5] * e;
        }
        dot /= se;
        out[obase + p] = 1.f / (1.f + __expf(-dot));
    }
}

extern "C" void kernel_launch(void* const* d_in, const int* in_sizes, int n_in,
                              void* d_out, int out_size, void* d_ws, size_t ws_size,
                              hipStream_t stream) {
    const float* test = (const float*)d_in[0];
    const float* attn = (const float*)d_in[1];
    const float* bases = (const float*)d_in[2];
    const float* sem = (const float*)d_in[3];
    float* out = (float*)d_out;
    char* w = (char*)d_ws;   // needs ~780 KB

    k_clear<<<5, 256, 0, stream>>>(w);
    k_hist<<<dim3(128, B_), 256, 0, stream>>>(test, w);
    k_thresh<<<1, 64, 0, stream>>>(w);
    k_collect<<<dim3(128, B_), 256, 0, stream>>>(test, w);
    k_sort<<<B_, 1024, 0, stream>>>(test, w);
    k_sup<<<dim3(64, B_), 256, 0, stream>>>(w);
    k_nms<<<B_, 64, 0, stream>>>(w, out);
    k_mask<<<dim3(B_ * MAXDET_, 8), 256, 0, stream>>>(test, attn, bases, sem, w, out);
}